// Round 3
// baseline (917.060 us; speedup 1.0000x reference)
//
#include <hip/hip_runtime.h>

#define N_NODES 100000
#define N_EDGES 1600000
#define NFEAT 128
#define NHID 64

#define BBITS 8                         // bucket = row >> 8  (256 rows/bucket)
#define NBUCK 391                       // ceil(100000 / 256)
#define BATCH 4096                      // edges per bin block
#define NBATCH ((N_EDGES + BATCH - 1) / BATCH)   // 391

// ---------------- GEMM: support = x @ W ----------------
__global__ __launch_bounds__(256) void gcn_gemm(const float* __restrict__ x,
                                                const float* __restrict__ W,
                                                float* __restrict__ support) {
  const int lane = threadIdx.x & 63;
  const int wave = __builtin_amdgcn_readfirstlane(threadIdx.x >> 6);
  const int node0 = blockIdx.x * 32 + wave * 8;
  const float* __restrict__ xr = x + (size_t)node0 * NFEAT;
  float acc[8];
#pragma unroll
  for (int n = 0; n < 8; ++n) acc[n] = 0.f;
#pragma unroll 4
  for (int k = 0; k < NFEAT; ++k) {
    const float wv = W[k * NHID + lane];
#pragma unroll
    for (int n = 0; n < 8; ++n)
      acc[n] = __builtin_fmaf(xr[(size_t)n * NFEAT + k], wv, acc[n]);
  }
#pragma unroll
  for (int n = 0; n < 8; ++n)
    support[(size_t)(node0 + n) * NHID + lane] = acc[n];
}

// ---------------- Stage 1: per-batch bucket histogram ----------------
// grid NBATCH x 512. hist_g[batch * NBUCK + bucket] (plain writes, no memset).
__global__ __launch_bounds__(512) void gcn_bucket_hist(const int* __restrict__ erow,
                                                       int* __restrict__ hist_g) {
  __shared__ int h[NBUCK];
  for (int t = threadIdx.x; t < NBUCK; t += 512) h[t] = 0;
  __syncthreads();
  const int base = blockIdx.x * BATCH;
  const int n = min(BATCH, N_EDGES - base);
  for (int j = threadIdx.x; j < n; j += 512)
    atomicAdd(&h[erow[base + j] >> BBITS], 1);
  __syncthreads();
  for (int t = threadIdx.x; t < NBUCK; t += 512)
    hist_g[(size_t)blockIdx.x * NBUCK + t] = h[t];
}

// ---------------- Stage 2: column scan over batches (in-place) ----------------
// grid NBUCK x 512; block k scans hist_g[:, k] -> exclusive offsets; tot[k] = sum.
__global__ __launch_bounds__(512) void gcn_colscan(int* __restrict__ hist_g,
                                                   int* __restrict__ tot) {
  __shared__ int sm[512];
  const int k = blockIdx.x;
  const int t = threadIdx.x;
  const int v = (t < NBATCH) ? hist_g[(size_t)t * NBUCK + k] : 0;
  sm[t] = v;
  __syncthreads();
  for (int off = 1; off < 512; off <<= 1) {
    const int xv = (t >= off) ? sm[t - off] : 0;
    __syncthreads();
    sm[t] += xv;
    __syncthreads();
  }
  if (t < NBATCH) hist_g[(size_t)t * NBUCK + k] = sm[t] - v;  // exclusive
  if (t == NBATCH - 1) tot[k] = sm[t];                        // inclusive total
}

// ---------------- Stage 3: bucket base scan ----------------
__global__ __launch_bounds__(512) void gcn_bucket_scan(const int* __restrict__ tot,
                                                       int* __restrict__ bstart) {
  __shared__ int sm[512];
  const int t = threadIdx.x;
  const int v = (t < NBUCK) ? tot[t] : 0;
  sm[t] = v;
  __syncthreads();
  for (int off = 1; off < 512; off <<= 1) {
    const int xv = (t >= off) ? sm[t - off] : 0;
    __syncthreads();
    sm[t] += xv;
    __syncthreads();
  }
  if (t < NBUCK) bstart[t] = sm[t] - v;
  if (t == NBUCK - 1) bstart[NBUCK] = sm[t];  // == N_EDGES
}

// ---------------- Stage 4: bin edges (counting sort by bucket) ----------------
// grid NBATCH x 512. Coalesced output: sorted-by-bucket staging in LDS,
// each batch writes disjoint contiguous slices per bucket (no atomics).
__global__ __launch_bounds__(512) void gcn_bin(const int* __restrict__ erow,
                                               const int* __restrict__ ecol,
                                               const float* __restrict__ eval_,
                                               const int* __restrict__ colofs,  // hist_g after colscan
                                               const int* __restrict__ bstart,
                                               int* __restrict__ eg) {
  __shared__ int h[NBUCK];     // hist, then dest_base
  __shared__ int ofs[NBUCK];   // local exclusive offsets
  __shared__ int sm[512];
  __shared__ int sr[BATCH];
  __shared__ int sc[BATCH];
  __shared__ int sv[BATCH];
  const int t = threadIdx.x;
  for (int i = t; i < NBUCK; i += 512) h[i] = 0;
  __syncthreads();
  const int base = blockIdx.x * BATCH;
  const int n = min(BATCH, N_EDGES - base);
  int myr[8], myc[8], myv[8], myrank[8];
#pragma unroll
  for (int u = 0; u < 8; ++u) {
    const int j = t + u * 512;
    if (j < n) {
      myr[u] = erow[base + j];
      myc[u] = ecol[base + j];
      myv[u] = __float_as_int(eval_[base + j]);
      myrank[u] = atomicAdd(&h[myr[u] >> BBITS], 1);
    }
  }
  __syncthreads();
  // exclusive scan of h -> ofs
  const int hv = (t < NBUCK) ? h[t] : 0;
  sm[t] = hv;
  __syncthreads();
  for (int off = 1; off < 512; off <<= 1) {
    const int xv = (t >= off) ? sm[t - off] : 0;
    __syncthreads();
    sm[t] += xv;
    __syncthreads();
  }
  if (t < NBUCK) ofs[t] = sm[t] - hv;
  __syncthreads();
  // stage sorted by bucket
#pragma unroll
  for (int u = 0; u < 8; ++u) {
    const int j = t + u * 512;
    if (j < n) {
      const int pos = ofs[myr[u] >> BBITS] + myrank[u];
      sr[pos] = myr[u];
      sc[pos] = myc[u];
      sv[pos] = myv[u];
    }
  }
  // dest_base[k] = global start of this batch's slice of bucket k, minus local start
  if (t < NBUCK) h[t] = bstart[t] + colofs[(size_t)blockIdx.x * NBUCK + t] - ofs[t];
  __syncthreads();
  // coalesced-run output: consecutive j in same bucket -> consecutive dest
  for (int j = t; j < n; j += 512) {
    const int r = sr[j];
    const int d = h[r >> BBITS] + j;
    eg[(size_t)d * 3 + 0] = r;
    eg[(size_t)d * 3 + 1] = sc[j];
    eg[(size_t)d * 3 + 2] = sv[j];
  }
}

// ---------------- Threefry-2x32 (JAX partitionable), key (0,42) ----------------
__device__ __forceinline__ unsigned rotl32(unsigned v, int r) {
  return (v << r) | (v >> (32 - r));
}

__device__ __forceinline__ unsigned threefry_draw(unsigned i) {
  const unsigned ks0 = 0u;
  const unsigned ks1 = 42u;
  const unsigned ks2 = 0x1BD11BDAu ^ 42u;
  unsigned x0 = 0u + ks0;
  unsigned x1 = i + ks1;
#define TF_ROUND(r) { x0 += x1; x1 = rotl32(x1, (r)); x1 ^= x0; }
  TF_ROUND(13) TF_ROUND(15) TF_ROUND(26) TF_ROUND(6)
  x0 += ks1; x1 += ks2 + 1u;
  TF_ROUND(17) TF_ROUND(29) TF_ROUND(16) TF_ROUND(24)
  x0 += ks2; x1 += ks0 + 2u;
  TF_ROUND(13) TF_ROUND(15) TF_ROUND(26) TF_ROUND(6)
  x0 += ks0; x1 += ks1 + 3u;
  TF_ROUND(17) TF_ROUND(29) TF_ROUND(16) TF_ROUND(24)
  x0 += ks1; x1 += ks2 + 4u;
  TF_ROUND(13) TF_ROUND(15) TF_ROUND(26) TF_ROUND(6)
  x0 += ks2; x1 += ks0 + 5u;
#undef TF_ROUND
  return x0 ^ x1;
}

// ---------------- Stage 5: aggregate per bucket in LDS + fused epilogue -------
// grid NBUCK x 512. 64 KB LDS accumulator (256 rows x 64 hid).
__global__ __launch_bounds__(512) void gcn_aggregate(const int* __restrict__ bstart,
                                                     const int* __restrict__ eg,
                                                     const float* __restrict__ support,
                                                     const float* __restrict__ b,
                                                     float* __restrict__ out) {
  __shared__ float accum[256 * NHID];  // 64 KB
  for (int i = threadIdx.x; i < 256 * NHID; i += 512) accum[i] = 0.f;
  __syncthreads();
  const int k = blockIdx.x;
  const int s = bstart[k];
  const int e = bstart[k + 1];
  const int wave = threadIdx.x >> 6;
  const int lane = threadIdx.x & 63;
  for (int i = s + wave; i < e; i += 8) {
    const int r = eg[(size_t)i * 3 + 0];
    const int c = eg[(size_t)i * 3 + 1];
    const float v = __int_as_float(eg[(size_t)i * 3 + 2]);
    const float sv = support[(size_t)c * NHID + lane];
    atomicAdd(&accum[(r & 255) * NHID + lane], v * sv);  // ds_add_f32, bank-conflict-free
  }
  __syncthreads();
  const int node0 = k << BBITS;
  for (int i = threadIdx.x; i < 256 * NHID; i += 512) {
    const int node = node0 + (i >> 6);
    if (node < N_NODES) {
      const int ln = i & 63;
      const float h = fmaxf(accum[i] + b[ln], 0.f);
      const unsigned idx = (unsigned)node * 64u + (unsigned)ln;
      const bool keep = (threefry_draw(idx) >> 31) == 0u;
      out[idx] = keep ? h * 2.0f : 0.0f;
    }
  }
}

extern "C" void kernel_launch(void* const* d_in, const int* in_sizes, int n_in,
                              void* d_out, int out_size, void* d_ws, size_t ws_size,
                              hipStream_t stream) {
  const float* x     = (const float*)d_in[0];
  const int*   erow  = (const int*)d_in[1];
  const int*   ecol  = (const int*)d_in[2];
  const float* eval_ = (const float*)d_in[3];
  const float* W     = (const float*)d_in[4];
  const float* b     = (const float*)d_in[5];
  float* out = (float*)d_out;

  // Workspace layout (bytes, 16-aligned):
  char* ws = (char*)d_ws;
  float* support = (float*)(ws);                 // 25,600,000
  int*   eg      = (int*)(ws + 25600000);        // 19,200,000 (1.6M x 12 B)
  int*   hist_g  = (int*)(ws + 44800000);        //    611,524 (+pad)
  int*   tot     = (int*)(ws + 45411536);        //      1,564
  int*   bstart  = (int*)(ws + 45413104);        //      1,568
  // total ~45.4 MB

  hipLaunchKernelGGL(gcn_gemm, dim3(N_NODES / 32), dim3(256), 0, stream, x, W, support);
  hipLaunchKernelGGL(gcn_bucket_hist, dim3(NBATCH), dim3(512), 0, stream, erow, hist_g);
  hipLaunchKernelGGL(gcn_colscan, dim3(NBUCK), dim3(512), 0, stream, hist_g, tot);
  hipLaunchKernelGGL(gcn_bucket_scan, dim3(1), dim3(512), 0, stream, tot, bstart);
  hipLaunchKernelGGL(gcn_bin, dim3(NBATCH), dim3(512), 0, stream,
                     erow, ecol, eval_, hist_g, bstart, eg);
  hipLaunchKernelGGL(gcn_aggregate, dim3(NBUCK), dim3(512), 0, stream,
                     bstart, eg, support, b, out);
}

// Round 4
// 271.361 us; speedup vs baseline: 3.3795x; 3.3795x over previous
//
#include <hip/hip_runtime.h>

#define N_NODES 100000
#define N_EDGES 1600000
#define NFEAT 128
#define NHID 64

#define BBITS 8                                  // bucket = row >> 8 (256 rows)
#define NBUCK 391                                // ceil(100000 / 256)
#define BATCH 4096                               // edges per bin block
#define NBATCH ((N_EDGES + BATCH - 1) / BATCH)   // 391
#define CMASK 0x1FFFF                            // 17 bits for col (< 131072)

// ---------------- GEMM: support = x @ W (float4 x loads) ----------------
__global__ __launch_bounds__(256) void gcn_gemm(const float* __restrict__ x,
                                                const float* __restrict__ W,
                                                float* __restrict__ support) {
  const int lane = threadIdx.x & 63;
  const int wave = __builtin_amdgcn_readfirstlane(threadIdx.x >> 6);
  const int node0 = blockIdx.x * 32 + wave * 8;
  const float4* __restrict__ xr4 = (const float4*)(x + (size_t)node0 * NFEAT);
  float acc[8];
#pragma unroll
  for (int n = 0; n < 8; ++n) acc[n] = 0.f;
  for (int k4 = 0; k4 < NFEAT / 4; ++k4) {
    float4 xv[8];
#pragma unroll
    for (int n = 0; n < 8; ++n) xv[n] = xr4[n * (NFEAT / 4) + k4];  // broadcast 16B
    float wv[4];
#pragma unroll
    for (int j = 0; j < 4; ++j) wv[j] = W[(4 * k4 + j) * NHID + lane];
#pragma unroll
    for (int n = 0; n < 8; ++n) {
      acc[n] = __builtin_fmaf(xv[n].x, wv[0], acc[n]);
      acc[n] = __builtin_fmaf(xv[n].y, wv[1], acc[n]);
      acc[n] = __builtin_fmaf(xv[n].z, wv[2], acc[n]);
      acc[n] = __builtin_fmaf(xv[n].w, wv[3], acc[n]);
    }
  }
#pragma unroll
  for (int n = 0; n < 8; ++n)
    support[(size_t)(node0 + n) * NHID + lane] = acc[n];
}

// ---------------- Stage 1: per-batch bucket histogram ----------------
__global__ __launch_bounds__(512) void gcn_bucket_hist(const int* __restrict__ erow,
                                                       int* __restrict__ hist_g) {
  __shared__ int h[NBUCK];
  for (int t = threadIdx.x; t < NBUCK; t += 512) h[t] = 0;
  __syncthreads();
  const int base = blockIdx.x * BATCH;
  const int n = min(BATCH, N_EDGES - base);
  for (int j = threadIdx.x; j < n; j += 512)
    atomicAdd(&h[erow[base + j] >> BBITS], 1);
  __syncthreads();
  for (int t = threadIdx.x; t < NBUCK; t += 512)
    hist_g[(size_t)blockIdx.x * NBUCK + t] = h[t];
}

// ---------------- Stage 2: column scan over batches (in-place) ----------------
__global__ __launch_bounds__(512) void gcn_colscan(int* __restrict__ hist_g,
                                                   int* __restrict__ tot) {
  __shared__ int sm[512];
  const int k = blockIdx.x;
  const int t = threadIdx.x;
  const int v = (t < NBATCH) ? hist_g[(size_t)t * NBUCK + k] : 0;
  sm[t] = v;
  __syncthreads();
  for (int off = 1; off < 512; off <<= 1) {
    const int xv = (t >= off) ? sm[t - off] : 0;
    __syncthreads();
    sm[t] += xv;
    __syncthreads();
  }
  if (t < NBATCH) hist_g[(size_t)t * NBUCK + k] = sm[t] - v;  // exclusive
  if (t == NBATCH - 1) tot[k] = sm[t];
}

// ---------------- Stage 3: bucket base scan (+ row_start sentinel) ------------
__global__ __launch_bounds__(512) void gcn_bucket_scan(const int* __restrict__ tot,
                                                       int* __restrict__ bstart,
                                                       int* __restrict__ row_start) {
  __shared__ int sm[512];
  const int t = threadIdx.x;
  const int v = (t < NBUCK) ? tot[t] : 0;
  sm[t] = v;
  __syncthreads();
  for (int off = 1; off < 512; off <<= 1) {
    const int xv = (t >= off) ? sm[t - off] : 0;
    __syncthreads();
    sm[t] += xv;
    __syncthreads();
  }
  if (t < NBUCK) bstart[t] = sm[t] - v;
  if (t == NBUCK - 1) bstart[NBUCK] = sm[t];
  if (t == 0) row_start[N_NODES] = N_EDGES;
}

// ---------------- Stage 4: bin edges by bucket (coalesced output) -------------
// eg[i] = { (r&255)<<17 | c , float_bits(val) }  (8 B records)
__global__ __launch_bounds__(512) void gcn_bin(const int* __restrict__ erow,
                                               const int* __restrict__ ecol,
                                               const float* __restrict__ eval_,
                                               const int* __restrict__ colofs,
                                               const int* __restrict__ bstart,
                                               int2* __restrict__ eg) {
  __shared__ int h[NBUCK];       // hist, then dest_base
  __shared__ int ofs[NBUCK];
  __shared__ int sm[512];
  __shared__ int spx[BATCH];
  __shared__ int sv[BATCH];
  __shared__ short sb[BATCH];
  const int t = threadIdx.x;
  for (int i = t; i < NBUCK; i += 512) h[i] = 0;
  __syncthreads();
  const int base = blockIdx.x * BATCH;
  const int n = min(BATCH, N_EDGES - base);
  int mypx[8], myv[8], myrank[8], myb[8];
#pragma unroll
  for (int u = 0; u < 8; ++u) {
    const int j = t + u * 512;
    if (j < n) {
      const int r = erow[base + j];
      mypx[u] = ((r & 255) << 17) | ecol[base + j];
      myv[u] = __float_as_int(eval_[base + j]);
      myb[u] = r >> BBITS;
      myrank[u] = atomicAdd(&h[myb[u]], 1);
    }
  }
  __syncthreads();
  const int hv = (t < NBUCK) ? h[t] : 0;
  sm[t] = hv;
  __syncthreads();
  for (int off = 1; off < 512; off <<= 1) {
    const int xv = (t >= off) ? sm[t - off] : 0;
    __syncthreads();
    sm[t] += xv;
    __syncthreads();
  }
  if (t < NBUCK) ofs[t] = sm[t] - hv;
  __syncthreads();
#pragma unroll
  for (int u = 0; u < 8; ++u) {
    const int j = t + u * 512;
    if (j < n) {
      const int pos = ofs[myb[u]] + myrank[u];
      spx[pos] = mypx[u];
      sv[pos] = myv[u];
      sb[pos] = (short)myb[u];
    }
  }
  if (t < NBUCK) h[t] = bstart[t] + colofs[(size_t)blockIdx.x * NBUCK + t] - ofs[t];
  __syncthreads();
  for (int j = t; j < n; j += 512) {
    const int d = h[sb[j]] + j;   // consecutive j in same bucket -> consecutive d
    eg[d] = make_int2(spx[j], sv[j]);
  }
}

// ---------------- Stage 5: in-place counting sort by row within bucket --------
// Reads all records into registers first, then scatters within the bucket's own
// slice (in-place safe; writes confined to one block's 32 KB window -> L2 merges).
__global__ __launch_bounds__(512) void gcn_rowsort(const int* __restrict__ bstart,
                                                   int2* __restrict__ eg,
                                                   int* __restrict__ row_start) {
  __shared__ int cnt[256];
  __shared__ int sm[256];
  __shared__ int rofs[256];
  const int t = threadIdx.x;
  const int k = blockIdx.x;
  if (t < 256) cnt[t] = 0;
  __syncthreads();
  const int s = bstart[k];
  const int n = bstart[k + 1] - s;
  int px[9], pv[9], rk[9];
#pragma unroll
  for (int u = 0; u < 9; ++u) {
    const int j = t + u * 512;
    if (j < n) {
      const int2 p = eg[s + j];
      px[u] = p.x;
      pv[u] = p.y;
      rk[u] = atomicAdd(&cnt[p.x >> 17], 1);
    }
  }
  __syncthreads();
  const int myc = (t < 256) ? cnt[t] : 0;
  if (t < 256) sm[t] = myc;
  __syncthreads();
  for (int off = 1; off < 256; off <<= 1) {
    int xv = 0;
    if (t >= off && t < 256) xv = sm[t - off];
    __syncthreads();
    if (t < 256) sm[t] += xv;
    __syncthreads();
  }
  if (t < 256) {
    rofs[t] = sm[t] - myc;  // exclusive
    const int node = (k << BBITS) + t;
    if (node < N_NODES) row_start[node] = s + sm[t] - myc;
  }
  __syncthreads();
#pragma unroll
  for (int u = 0; u < 9; ++u) {
    const int j = t + u * 512;
    if (j < n) {
      const int d = s + rofs[px[u] >> 17] + rk[u];
      eg[d] = make_int2(px[u] & CMASK, pv[u]);   // clean col
    }
  }
}

// ---------------- Threefry-2x32 (JAX partitionable), key (0,42) ----------------
__device__ __forceinline__ unsigned rotl32(unsigned v, int r) {
  return (v << r) | (v >> (32 - r));
}

__device__ __forceinline__ unsigned threefry_draw(unsigned i) {
  const unsigned ks0 = 0u;
  const unsigned ks1 = 42u;
  const unsigned ks2 = 0x1BD11BDAu ^ 42u;
  unsigned x0 = 0u + ks0;
  unsigned x1 = i + ks1;
#define TF_ROUND(r) { x0 += x1; x1 = rotl32(x1, (r)); x1 ^= x0; }
  TF_ROUND(13) TF_ROUND(15) TF_ROUND(26) TF_ROUND(6)
  x0 += ks1; x1 += ks2 + 1u;
  TF_ROUND(17) TF_ROUND(29) TF_ROUND(16) TF_ROUND(24)
  x0 += ks2; x1 += ks0 + 2u;
  TF_ROUND(13) TF_ROUND(15) TF_ROUND(26) TF_ROUND(6)
  x0 += ks0; x1 += ks1 + 3u;
  TF_ROUND(17) TF_ROUND(29) TF_ROUND(16) TF_ROUND(24)
  x0 += ks1; x1 += ks2 + 4u;
  TF_ROUND(13) TF_ROUND(15) TF_ROUND(26) TF_ROUND(6)
  x0 += ks2; x1 += ks0 + 5u;
#undef TF_ROUND
  return x0 ^ x1;
}

// ---------------- Stage 6: aggregate (wave/node, 4 edges in flight) -----------
__global__ __launch_bounds__(256) void gcn_aggregate(const int* __restrict__ row_start,
                                                     const int2* __restrict__ eg,
                                                     const float* __restrict__ support,
                                                     const float* __restrict__ b,
                                                     float* __restrict__ out) {
  const int node = (int)((blockIdx.x * 256u + threadIdx.x) >> 6);
  const int lane = threadIdx.x & 63;
  const int grp = lane >> 4;     // edge slot 0..3
  const int hq = lane & 15;      // float4 index within hid row
  const int s = row_start[node];
  const int e = row_start[node + 1];
  float4 acc = make_float4(0.f, 0.f, 0.f, 0.f);
  for (int i = s; i < e; i += 4) {
    const int idx = i + grp;
    const int2 p = (idx < e) ? eg[idx] : make_int2(0, 0);  // val 0 pad -> no-op
    const float4 sv = ((const float4*)support)[(size_t)p.x * 16 + hq];
    const float v = __int_as_float(p.y);
    acc.x = __builtin_fmaf(v, sv.x, acc.x);
    acc.y = __builtin_fmaf(v, sv.y, acc.y);
    acc.z = __builtin_fmaf(v, sv.z, acc.z);
    acc.w = __builtin_fmaf(v, sv.w, acc.w);
  }
  // reduce across the 4 edge groups
  acc.x += __shfl_xor(acc.x, 16); acc.y += __shfl_xor(acc.y, 16);
  acc.z += __shfl_xor(acc.z, 16); acc.w += __shfl_xor(acc.w, 16);
  acc.x += __shfl_xor(acc.x, 32); acc.y += __shfl_xor(acc.y, 32);
  acc.z += __shfl_xor(acc.z, 32); acc.w += __shfl_xor(acc.w, 32);
  // redistribute: lane L takes component L&3 of float4 held at lane L>>2
  const int src = lane >> 2;
  const float r0 = __shfl(acc.x, src);
  const float r1 = __shfl(acc.y, src);
  const float r2 = __shfl(acc.z, src);
  const float r3 = __shfl(acc.w, src);
  const int cs = lane & 3;
  const float aval = (cs == 0) ? r0 : (cs == 1) ? r1 : (cs == 2) ? r2 : r3;
  const float h = fmaxf(aval + b[lane], 0.f);
  const unsigned idxg = (unsigned)node * 64u + (unsigned)lane;
  const bool keep = (threefry_draw(idxg) >> 31) == 0u;
  out[idxg] = keep ? h * 2.0f : 0.0f;
}

extern "C" void kernel_launch(void* const* d_in, const int* in_sizes, int n_in,
                              void* d_out, int out_size, void* d_ws, size_t ws_size,
                              hipStream_t stream) {
  const float* x     = (const float*)d_in[0];
  const int*   erow  = (const int*)d_in[1];
  const int*   ecol  = (const int*)d_in[2];
  const float* eval_ = (const float*)d_in[3];
  const float* W     = (const float*)d_in[4];
  const float* b     = (const float*)d_in[5];
  float* out = (float*)d_out;

  // Workspace layout (bytes, 16-aligned), total ~39.4 MB:
  char* ws = (char*)d_ws;
  float* support  = (float*)(ws);                 // 25,600,000
  int2*  eg       = (int2*)(ws + 25600000);       // 12,800,000
  int*   hist_g   = (int*)(ws + 38400000);        //    611,524
  int*   tot      = (int*)(ws + 39011536);        //      1,564
  int*   bstart   = (int*)(ws + 39013104);        //      1,568
  int*   row_start= (int*)(ws + 39014672);        //    400,004

  hipLaunchKernelGGL(gcn_gemm, dim3(N_NODES / 32), dim3(256), 0, stream, x, W, support);
  hipLaunchKernelGGL(gcn_bucket_hist, dim3(NBATCH), dim3(512), 0, stream, erow, hist_g);
  hipLaunchKernelGGL(gcn_colscan, dim3(NBUCK), dim3(512), 0, stream, hist_g, tot);
  hipLaunchKernelGGL(gcn_bucket_scan, dim3(1), dim3(512), 0, stream, tot, bstart, row_start);
  hipLaunchKernelGGL(gcn_bin, dim3(NBATCH), dim3(512), 0, stream,
                     erow, ecol, eval_, hist_g, bstart, eg);
  hipLaunchKernelGGL(gcn_rowsort, dim3(NBUCK), dim3(512), 0, stream,
                     bstart, eg, row_start);
  hipLaunchKernelGGL(gcn_aggregate, dim3(N_NODES / 4), dim3(256), 0, stream,
                     row_start, eg, support, b, out);
}

// Round 5
// 222.494 us; speedup vs baseline: 4.1217x; 1.2196x over previous
//
#include <hip/hip_runtime.h>

#define N_NODES 100000
#define N_EDGES 1600000
#define NFEAT 128
#define NHID 64

#define BBITS 8                                  // bucket = row >> 8 (256 rows)
#define NBUCK 391                                // ceil(100000 / 256)
#define BATCH 4096                               // edges per bin block
#define NBATCH ((N_EDGES + BATCH - 1) / BATCH)   // 391
#define CMASK 0x1FFFF                            // 17 bits for col (< 131072)

// fp32 -> bf16 round-to-nearest-even
__device__ __forceinline__ unsigned short f2bf(float f) {
  unsigned u = __float_as_uint(f);
  u += 0x7fffu + ((u >> 16) & 1u);
  return (unsigned short)(u >> 16);
}

// ---------------- GEMM: support = x @ W (LDS-staged x, bf16 out) ----------------
__global__ __launch_bounds__(256) void gcn_gemm(const float* __restrict__ x,
                                                const float* __restrict__ W,
                                                unsigned short* __restrict__ support_h) {
  __shared__ float lds_x[32 * NFEAT];  // 16 KB
  const int t = threadIdx.x;
  const int node0 = blockIdx.x * 32;
  const float4* __restrict__ xg = (const float4*)(x + (size_t)node0 * NFEAT);
  float4* lds4 = (float4*)lds_x;
#pragma unroll
  for (int i = 0; i < 4; ++i)
    lds4[i * 256 + t] = xg[i * 256 + t];      // fully coalesced stage
  __syncthreads();
  const int lane = t & 63;
  const int wave = t >> 6;
  const float4* lx = (const float4*)lds_x;
  float acc[8];
#pragma unroll
  for (int n = 0; n < 8; ++n) acc[n] = 0.f;
#pragma unroll 4
  for (int k4 = 0; k4 < NFEAT / 4; ++k4) {
    float wv[4];
#pragma unroll
    for (int j = 0; j < 4; ++j) wv[j] = W[(4 * k4 + j) * NHID + lane];
#pragma unroll
    for (int n = 0; n < 8; ++n) {
      const float4 xv = lx[(wave * 8 + n) * (NFEAT / 4) + k4];  // LDS broadcast
      acc[n] = __builtin_fmaf(xv.x, wv[0], acc[n]);
      acc[n] = __builtin_fmaf(xv.y, wv[1], acc[n]);
      acc[n] = __builtin_fmaf(xv.z, wv[2], acc[n]);
      acc[n] = __builtin_fmaf(xv.w, wv[3], acc[n]);
    }
  }
#pragma unroll
  for (int n = 0; n < 8; ++n)
    support_h[(size_t)(node0 + wave * 8 + n) * NHID + lane] = f2bf(acc[n]);
}

// ---------------- Stage 1: per-batch bucket histogram ----------------
__global__ __launch_bounds__(512) void gcn_bucket_hist(const int* __restrict__ erow,
                                                       int* __restrict__ hist_g) {
  __shared__ int h[NBUCK];
  for (int t = threadIdx.x; t < NBUCK; t += 512) h[t] = 0;
  __syncthreads();
  const int base = blockIdx.x * BATCH;
  const int n = min(BATCH, N_EDGES - base);
  for (int j = threadIdx.x; j < n; j += 512)
    atomicAdd(&h[erow[base + j] >> BBITS], 1);
  __syncthreads();
  for (int t = threadIdx.x; t < NBUCK; t += 512)
    hist_g[(size_t)blockIdx.x * NBUCK + t] = h[t];
}

// ---------------- Stage 2: column scan over batches (in-place) ----------------
__global__ __launch_bounds__(512) void gcn_colscan(int* __restrict__ hist_g,
                                                   int* __restrict__ tot) {
  __shared__ int sm[512];
  const int k = blockIdx.x;
  const int t = threadIdx.x;
  const int v = (t < NBATCH) ? hist_g[(size_t)t * NBUCK + k] : 0;
  sm[t] = v;
  __syncthreads();
  for (int off = 1; off < 512; off <<= 1) {
    const int xv = (t >= off) ? sm[t - off] : 0;
    __syncthreads();
    sm[t] += xv;
    __syncthreads();
  }
  if (t < NBATCH) hist_g[(size_t)t * NBUCK + k] = sm[t] - v;  // exclusive
  if (t == NBATCH - 1) tot[k] = sm[t];
}

// ---------------- Stage 3: bucket base scan (+ row_start sentinel) ------------
__global__ __launch_bounds__(512) void gcn_bucket_scan(const int* __restrict__ tot,
                                                       int* __restrict__ bstart,
                                                       int* __restrict__ row_start) {
  __shared__ int sm[512];
  const int t = threadIdx.x;
  const int v = (t < NBUCK) ? tot[t] : 0;
  sm[t] = v;
  __syncthreads();
  for (int off = 1; off < 512; off <<= 1) {
    const int xv = (t >= off) ? sm[t - off] : 0;
    __syncthreads();
    sm[t] += xv;
    __syncthreads();
  }
  if (t < NBUCK) bstart[t] = sm[t] - v;
  if (t == NBUCK - 1) bstart[NBUCK] = sm[t];
  if (t == 0) row_start[N_NODES] = N_EDGES;
}

// ---------------- Stage 4: bin edges by bucket (coalesced output) -------------
__global__ __launch_bounds__(512) void gcn_bin(const int* __restrict__ erow,
                                               const int* __restrict__ ecol,
                                               const float* __restrict__ eval_,
                                               const int* __restrict__ colofs,
                                               const int* __restrict__ bstart,
                                               int2* __restrict__ eg) {
  __shared__ int h[NBUCK];       // hist, then dest_base
  __shared__ int ofs[NBUCK];
  __shared__ int sm[512];
  __shared__ int spx[BATCH];
  __shared__ int sv[BATCH];
  __shared__ short sb[BATCH];
  const int t = threadIdx.x;
  for (int i = t; i < NBUCK; i += 512) h[i] = 0;
  __syncthreads();
  const int base = blockIdx.x * BATCH;
  const int n = min(BATCH, N_EDGES - base);
  int mypx[8], myv[8], myrank[8], myb[8];
#pragma unroll
  for (int u = 0; u < 8; ++u) {
    const int j = t + u * 512;
    if (j < n) {
      const int r = erow[base + j];
      mypx[u] = ((r & 255) << 17) | ecol[base + j];
      myv[u] = __float_as_int(eval_[base + j]);
      myb[u] = r >> BBITS;
      myrank[u] = atomicAdd(&h[myb[u]], 1);
    }
  }
  __syncthreads();
  const int hv = (t < NBUCK) ? h[t] : 0;
  sm[t] = hv;
  __syncthreads();
  for (int off = 1; off < 512; off <<= 1) {
    const int xv = (t >= off) ? sm[t - off] : 0;
    __syncthreads();
    sm[t] += xv;
    __syncthreads();
  }
  if (t < NBUCK) ofs[t] = sm[t] - hv;
  __syncthreads();
#pragma unroll
  for (int u = 0; u < 8; ++u) {
    const int j = t + u * 512;
    if (j < n) {
      const int pos = ofs[myb[u]] + myrank[u];
      spx[pos] = mypx[u];
      sv[pos] = myv[u];
      sb[pos] = (short)myb[u];
    }
  }
  if (t < NBUCK) h[t] = bstart[t] + colofs[(size_t)blockIdx.x * NBUCK + t] - ofs[t];
  __syncthreads();
  for (int j = t; j < n; j += 512) {
    const int d = h[sb[j]] + j;   // consecutive j in same bucket -> consecutive d
    eg[d] = make_int2(spx[j], sv[j]);
  }
}

// ---------------- Stage 5: in-place counting sort by row within bucket --------
__global__ __launch_bounds__(512) void gcn_rowsort(const int* __restrict__ bstart,
                                                   int2* __restrict__ eg,
                                                   int* __restrict__ row_start) {
  __shared__ int cnt[256];
  __shared__ int sm[256];
  __shared__ int rofs[256];
  const int t = threadIdx.x;
  const int k = blockIdx.x;
  if (t < 256) cnt[t] = 0;
  __syncthreads();
  const int s = bstart[k];
  const int n = bstart[k + 1] - s;
  int px[9], pv[9], rk[9];
#pragma unroll
  for (int u = 0; u < 9; ++u) {
    const int j = t + u * 512;
    if (j < n) {
      const int2 p = eg[s + j];
      px[u] = p.x;
      pv[u] = p.y;
      rk[u] = atomicAdd(&cnt[p.x >> 17], 1);
    }
  }
  __syncthreads();
  const int myc = (t < 256) ? cnt[t] : 0;
  if (t < 256) sm[t] = myc;
  __syncthreads();
  for (int off = 1; off < 256; off <<= 1) {
    int xv = 0;
    if (t >= off && t < 256) xv = sm[t - off];
    __syncthreads();
    if (t < 256) sm[t] += xv;
    __syncthreads();
  }
  if (t < 256) {
    rofs[t] = sm[t] - myc;  // exclusive
    const int node = (k << BBITS) + t;
    if (node < N_NODES) row_start[node] = s + sm[t] - myc;
  }
  __syncthreads();
#pragma unroll
  for (int u = 0; u < 9; ++u) {
    const int j = t + u * 512;
    if (j < n) {
      const int d = s + rofs[px[u] >> 17] + rk[u];
      eg[d] = make_int2(px[u] & CMASK, pv[u]);   // clean col
    }
  }
}

// ---------------- Threefry-2x32 (JAX partitionable), key (0,42) ----------------
__device__ __forceinline__ unsigned rotl32(unsigned v, int r) {
  return (v << r) | (v >> (32 - r));
}

__device__ __forceinline__ unsigned threefry_draw(unsigned i) {
  const unsigned ks0 = 0u;
  const unsigned ks1 = 42u;
  const unsigned ks2 = 0x1BD11BDAu ^ 42u;
  unsigned x0 = 0u + ks0;
  unsigned x1 = i + ks1;
#define TF_ROUND(r) { x0 += x1; x1 = rotl32(x1, (r)); x1 ^= x0; }
  TF_ROUND(13) TF_ROUND(15) TF_ROUND(26) TF_ROUND(6)
  x0 += ks1; x1 += ks2 + 1u;
  TF_ROUND(17) TF_ROUND(29) TF_ROUND(16) TF_ROUND(24)
  x0 += ks2; x1 += ks0 + 2u;
  TF_ROUND(13) TF_ROUND(15) TF_ROUND(26) TF_ROUND(6)
  x0 += ks0; x1 += ks1 + 3u;
  TF_ROUND(17) TF_ROUND(29) TF_ROUND(16) TF_ROUND(24)
  x0 += ks1; x1 += ks2 + 4u;
  TF_ROUND(13) TF_ROUND(15) TF_ROUND(26) TF_ROUND(6)
  x0 += ks2; x1 += ks0 + 5u;
#undef TF_ROUND
  return x0 ^ x1;
}

// ---------------- Stage 6: aggregate (wave/node, 8 edges in flight, bf16) -----
__global__ __launch_bounds__(256) void gcn_aggregate(const int* __restrict__ row_start,
                                                     const int2* __restrict__ eg,
                                                     const unsigned short* __restrict__ support_h,
                                                     const float* __restrict__ b,
                                                     float* __restrict__ out) {
  const int node = (int)((blockIdx.x * 256u + threadIdx.x) >> 6);
  const int lane = threadIdx.x & 63;
  const int grp = lane >> 3;     // edge slot 0..7
  const int sub = lane & 7;      // 8 bf16 feats each (16 B)
  const int s = row_start[node];
  const int e = row_start[node + 1];
  float acc[8];
#pragma unroll
  for (int j = 0; j < 8; ++j) acc[j] = 0.f;
  for (int i = s; i < e; i += 8) {
    const int idx = i + grp;
    const int2 p = (idx < e) ? eg[idx] : make_int2(0, 0);  // val 0 pad -> no-op
    const uint4 q = ((const uint4*)support_h)[(size_t)p.x * 8 + sub];
    const float v = __int_as_float(p.y);
    const float f0 = __uint_as_float(q.x << 16);
    const float f1 = __uint_as_float(q.x & 0xffff0000u);
    const float f2 = __uint_as_float(q.y << 16);
    const float f3 = __uint_as_float(q.y & 0xffff0000u);
    const float f4 = __uint_as_float(q.z << 16);
    const float f5 = __uint_as_float(q.z & 0xffff0000u);
    const float f6 = __uint_as_float(q.w << 16);
    const float f7 = __uint_as_float(q.w & 0xffff0000u);
    acc[0] = __builtin_fmaf(v, f0, acc[0]);
    acc[1] = __builtin_fmaf(v, f1, acc[1]);
    acc[2] = __builtin_fmaf(v, f2, acc[2]);
    acc[3] = __builtin_fmaf(v, f3, acc[3]);
    acc[4] = __builtin_fmaf(v, f4, acc[4]);
    acc[5] = __builtin_fmaf(v, f5, acc[5]);
    acc[6] = __builtin_fmaf(v, f6, acc[6]);
    acc[7] = __builtin_fmaf(v, f7, acc[7]);
  }
  // reduce across the 8 edge groups (grp bits = lane bits 3..5)
#pragma unroll
  for (int m = 8; m <= 32; m <<= 1) {
#pragma unroll
    for (int j = 0; j < 8; ++j) acc[j] += __shfl_xor(acc[j], m);
  }
  // redistribute: feat f = lane; holder sub = lane>>3, component j = lane&7
  const int src = lane >> 3;
  float r[8];
#pragma unroll
  for (int j = 0; j < 8; ++j) r[j] = __shfl(acc[j], src);
  const int js = lane & 7;
  float aval = r[0];
  aval = (js == 1) ? r[1] : aval;
  aval = (js == 2) ? r[2] : aval;
  aval = (js == 3) ? r[3] : aval;
  aval = (js == 4) ? r[4] : aval;
  aval = (js == 5) ? r[5] : aval;
  aval = (js == 6) ? r[6] : aval;
  aval = (js == 7) ? r[7] : aval;
  const float h = fmaxf(aval + b[lane], 0.f);
  const unsigned idxg = (unsigned)node * 64u + (unsigned)lane;
  const bool keep = (threefry_draw(idxg) >> 31) == 0u;
  out[idxg] = keep ? h * 2.0f : 0.0f;
}

extern "C" void kernel_launch(void* const* d_in, const int* in_sizes, int n_in,
                              void* d_out, int out_size, void* d_ws, size_t ws_size,
                              hipStream_t stream) {
  const float* x     = (const float*)d_in[0];
  const int*   erow  = (const int*)d_in[1];
  const int*   ecol  = (const int*)d_in[2];
  const float* eval_ = (const float*)d_in[3];
  const float* W     = (const float*)d_in[4];
  const float* b     = (const float*)d_in[5];
  float* out = (float*)d_out;

  // Workspace layout (bytes, 16-aligned):
  char* ws = (char*)d_ws;
  unsigned short* support_h = (unsigned short*)(ws);  // 12,800,000 (bf16)
  int2*  eg       = (int2*)(ws + 25600000);           // 12,800,000
  int*   hist_g   = (int*)(ws + 38400000);            //    611,524
  int*   tot      = (int*)(ws + 39011536);            //      1,564
  int*   bstart   = (int*)(ws + 39013104);            //      1,568
  int*   row_start= (int*)(ws + 39014672);            //    400,004

  hipLaunchKernelGGL(gcn_gemm, dim3(N_NODES / 32), dim3(256), 0, stream, x, W, support_h);
  hipLaunchKernelGGL(gcn_bucket_hist, dim3(NBATCH), dim3(512), 0, stream, erow, hist_g);
  hipLaunchKernelGGL(gcn_colscan, dim3(NBUCK), dim3(512), 0, stream, hist_g, tot);
  hipLaunchKernelGGL(gcn_bucket_scan, dim3(1), dim3(512), 0, stream, tot, bstart, row_start);
  hipLaunchKernelGGL(gcn_bin, dim3(NBATCH), dim3(512), 0, stream,
                     erow, ecol, eval_, hist_g, bstart, eg);
  hipLaunchKernelGGL(gcn_rowsort, dim3(NBUCK), dim3(512), 0, stream,
                     bstart, eg, row_start);
  hipLaunchKernelGGL(gcn_aggregate, dim3(N_NODES / 4), dim3(256), 0, stream,
                     row_start, eg, support_h, b, out);
}

// Round 6
// 211.617 us; speedup vs baseline: 4.3336x; 1.0514x over previous
//
#include <hip/hip_runtime.h>

#define N_NODES 100000
#define N_EDGES 1600000
#define NFEAT 128
#define NHID 64

#define BBITS 8                                  // bucket = row >> 8 (256 rows)
#define NBUCK 391                                // ceil(100000 / 256)
#define BATCH 4096                               // edges per bin block
#define NBATCH ((N_EDGES + BATCH - 1) / BATCH)   // 391
#define CMASK 0x1FFFF                            // 17 bits for col (< 131072)

typedef __attribute__((ext_vector_type(8))) short short8;
typedef __attribute__((ext_vector_type(4))) float f32x4;

// fp32 -> bf16 round-to-nearest-even
__device__ __forceinline__ unsigned short f2bf(float f) {
  unsigned u = __float_as_uint(f);
  u += 0x7fffu + ((u >> 16) & 1u);
  return (unsigned short)(u >> 16);
}

// ---------------- Wt: W[k][n] fp32 -> Wt[n][k] bf16 (done once, 16 KB) -------
__global__ __launch_bounds__(256) void gcn_wt(const float* __restrict__ W,
                                              unsigned short* __restrict__ wt) {
  const int i = blockIdx.x * 256 + threadIdx.x;   // 32 blocks x 256 = 8192
  const int n = i >> 7;
  const int k = i & 127;
  wt[i] = f2bf(W[k * NHID + n]);
}

// ---------------- GEMM: support = x @ W via MFMA bf16 ----------------
// Block = 64 nodes (32 KB LDS staging). 4 waves; wave w computes nodes
// node0+w*16 .. +15 over all 64 hid: 4 n-tiles x 4 k-chunks of 16x16x32.
__global__ __launch_bounds__(256) void gcn_gemm(const float* __restrict__ x,
                                                const unsigned short* __restrict__ wt,
                                                unsigned short* __restrict__ support_h) {
  __shared__ float ldsx[64 * NFEAT];  // 32 KB
  const int t = threadIdx.x;
  const int node0 = blockIdx.x * 64;
  const float4* __restrict__ gx = (const float4*)(x + (size_t)node0 * NFEAT);
  float4* lx4 = (float4*)ldsx;
  const int limit4 = (N_NODES - node0) * (NFEAT / 4);  // float4s available
#pragma unroll
  for (int i = 0; i < 8; ++i) {
    const int idx = i * 256 + t;
    if (idx < limit4) lx4[idx] = gx[idx];
  }
  __syncthreads();
  const int wv = t >> 6;
  const int lane = t & 63;
  const int quad = lane >> 4;
  const int nl = lane & 15;
  const int mrow = wv * 16 + nl;      // A-operand row (m = lane&15)
  f32x4 acc[4];
#pragma unroll
  for (int nt = 0; nt < 4; ++nt)
#pragma unroll
    for (int r = 0; r < 4; ++r) acc[nt][r] = 0.f;
#pragma unroll
  for (int kc = 0; kc < 4; ++kc) {
    const float* ap = &ldsx[mrow * NFEAT + kc * 32 + quad * 8];
    const float4 a0 = *(const float4*)ap;
    const float4 a1 = *(const float4*)(ap + 4);
    union { short8 v; unsigned short s[8]; } au;
    au.s[0] = f2bf(a0.x); au.s[1] = f2bf(a0.y);
    au.s[2] = f2bf(a0.z); au.s[3] = f2bf(a0.w);
    au.s[4] = f2bf(a1.x); au.s[5] = f2bf(a1.y);
    au.s[6] = f2bf(a1.z); au.s[7] = f2bf(a1.w);
#pragma unroll
    for (int nt = 0; nt < 4; ++nt) {
      const short8 bf = *(const short8*)(wt + (size_t)(nt * 16 + nl) * NFEAT +
                                         kc * 32 + quad * 8);
      acc[nt] = __builtin_amdgcn_mfma_f32_16x16x32_bf16(au.v, bf, acc[nt], 0, 0, 0);
    }
  }
  // C/D: row = quad*4 + reg (node), col = lane&15 (hid within n-tile)
#pragma unroll
  for (int nt = 0; nt < 4; ++nt)
#pragma unroll
    for (int r = 0; r < 4; ++r) {
      const int node = node0 + wv * 16 + quad * 4 + r;
      if (node < N_NODES)
        support_h[(size_t)node * NHID + nt * 16 + nl] = f2bf(acc[nt][r]);
    }
}

// ---------------- Stage 1: per-batch bucket histogram ----------------
__global__ __launch_bounds__(512) void gcn_bucket_hist(const int* __restrict__ erow,
                                                       int* __restrict__ hist_g) {
  __shared__ int h[NBUCK];
  for (int t = threadIdx.x; t < NBUCK; t += 512) h[t] = 0;
  __syncthreads();
  const int base = blockIdx.x * BATCH;
  const int n = min(BATCH, N_EDGES - base);
  for (int j = threadIdx.x; j < n; j += 512)
    atomicAdd(&h[erow[base + j] >> BBITS], 1);
  __syncthreads();
  for (int t = threadIdx.x; t < NBUCK; t += 512)
    hist_g[(size_t)blockIdx.x * NBUCK + t] = h[t];
}

// ---------------- Stage 2: column scan over batches (in-place) ----------------
__global__ __launch_bounds__(512) void gcn_colscan(int* __restrict__ hist_g,
                                                   int* __restrict__ tot) {
  __shared__ int sm[512];
  const int k = blockIdx.x;
  const int t = threadIdx.x;
  const int v = (t < NBATCH) ? hist_g[(size_t)t * NBUCK + k] : 0;
  sm[t] = v;
  __syncthreads();
  for (int off = 1; off < 512; off <<= 1) {
    const int xv = (t >= off) ? sm[t - off] : 0;
    __syncthreads();
    sm[t] += xv;
    __syncthreads();
  }
  if (t < NBATCH) hist_g[(size_t)t * NBUCK + k] = sm[t] - v;  // exclusive
  if (t == NBATCH - 1) tot[k] = sm[t];
}

// ---------------- Stage 3: bucket base scan (+ row_start sentinel) ------------
__global__ __launch_bounds__(512) void gcn_bucket_scan(const int* __restrict__ tot,
                                                       int* __restrict__ bstart,
                                                       int* __restrict__ row_start) {
  __shared__ int sm[512];
  const int t = threadIdx.x;
  const int v = (t < NBUCK) ? tot[t] : 0;
  sm[t] = v;
  __syncthreads();
  for (int off = 1; off < 512; off <<= 1) {
    const int xv = (t >= off) ? sm[t - off] : 0;
    __syncthreads();
    sm[t] += xv;
    __syncthreads();
  }
  if (t < NBUCK) bstart[t] = sm[t] - v;
  if (t == NBUCK - 1) bstart[NBUCK] = sm[t];
  if (t == 0) row_start[N_NODES] = N_EDGES;
}

// ---------------- Stage 4: bin edges by bucket (coalesced output) -------------
__global__ __launch_bounds__(512) void gcn_bin(const int* __restrict__ erow,
                                               const int* __restrict__ ecol,
                                               const float* __restrict__ eval_,
                                               const int* __restrict__ colofs,
                                               const int* __restrict__ bstart,
                                               int2* __restrict__ eg) {
  __shared__ int h[NBUCK];       // hist, then dest_base
  __shared__ int ofs[NBUCK];
  __shared__ int sm[512];
  __shared__ int spx[BATCH];
  __shared__ int sv[BATCH];
  __shared__ short sb[BATCH];
  const int t = threadIdx.x;
  for (int i = t; i < NBUCK; i += 512) h[i] = 0;
  __syncthreads();
  const int base = blockIdx.x * BATCH;
  const int n = min(BATCH, N_EDGES - base);
  int mypx[8], myv[8], myrank[8], myb[8];
#pragma unroll
  for (int u = 0; u < 8; ++u) {
    const int j = t + u * 512;
    if (j < n) {
      const int r = erow[base + j];
      mypx[u] = ((r & 255) << 17) | ecol[base + j];
      myv[u] = __float_as_int(eval_[base + j]);
      myb[u] = r >> BBITS;
      myrank[u] = atomicAdd(&h[myb[u]], 1);
    }
  }
  __syncthreads();
  const int hv = (t < NBUCK) ? h[t] : 0;
  sm[t] = hv;
  __syncthreads();
  for (int off = 1; off < 512; off <<= 1) {
    const int xv = (t >= off) ? sm[t - off] : 0;
    __syncthreads();
    sm[t] += xv;
    __syncthreads();
  }
  if (t < NBUCK) ofs[t] = sm[t] - hv;
  __syncthreads();
#pragma unroll
  for (int u = 0; u < 8; ++u) {
    const int j = t + u * 512;
    if (j < n) {
      const int pos = ofs[myb[u]] + myrank[u];
      spx[pos] = mypx[u];
      sv[pos] = myv[u];
      sb[pos] = (short)myb[u];
    }
  }
  if (t < NBUCK) h[t] = bstart[t] + colofs[(size_t)blockIdx.x * NBUCK + t] - ofs[t];
  __syncthreads();
  for (int j = t; j < n; j += 512) {
    const int d = h[sb[j]] + j;   // consecutive j in same bucket -> consecutive d
    eg[d] = make_int2(spx[j], sv[j]);
  }
}

// ---------------- Stage 5: in-place counting sort by row within bucket --------
__global__ __launch_bounds__(512) void gcn_rowsort(const int* __restrict__ bstart,
                                                   int2* __restrict__ eg,
                                                   int* __restrict__ row_start) {
  __shared__ int cnt[256];
  __shared__ int sm[256];
  __shared__ int rofs[256];
  const int t = threadIdx.x;
  const int k = blockIdx.x;
  if (t < 256) cnt[t] = 0;
  __syncthreads();
  const int s = bstart[k];
  const int n = bstart[k + 1] - s;
  int px[9], pv[9], rk[9];
#pragma unroll
  for (int u = 0; u < 9; ++u) {
    const int j = t + u * 512;
    if (j < n) {
      const int2 p = eg[s + j];
      px[u] = p.x;
      pv[u] = p.y;
      rk[u] = atomicAdd(&cnt[p.x >> 17], 1);
    }
  }
  __syncthreads();
  const int myc = (t < 256) ? cnt[t] : 0;
  if (t < 256) sm[t] = myc;
  __syncthreads();
  for (int off = 1; off < 256; off <<= 1) {
    int xv = 0;
    if (t >= off && t < 256) xv = sm[t - off];
    __syncthreads();
    if (t < 256) sm[t] += xv;
    __syncthreads();
  }
  if (t < 256) {
    rofs[t] = sm[t] - myc;  // exclusive
    const int node = (k << BBITS) + t;
    if (node < N_NODES) row_start[node] = s + sm[t] - myc;
  }
  __syncthreads();
#pragma unroll
  for (int u = 0; u < 9; ++u) {
    const int j = t + u * 512;
    if (j < n) {
      const int d = s + rofs[px[u] >> 17] + rk[u];
      eg[d] = make_int2(px[u] & CMASK, pv[u]);   // clean col
    }
  }
}

// ---------------- Threefry-2x32 (JAX partitionable), key (0,42) ----------------
__device__ __forceinline__ unsigned rotl32(unsigned v, int r) {
  return (v << r) | (v >> (32 - r));
}

__device__ __forceinline__ unsigned threefry_draw(unsigned i) {
  const unsigned ks0 = 0u;
  const unsigned ks1 = 42u;
  const unsigned ks2 = 0x1BD11BDAu ^ 42u;
  unsigned x0 = 0u + ks0;
  unsigned x1 = i + ks1;
#define TF_ROUND(r) { x0 += x1; x1 = rotl32(x1, (r)); x1 ^= x0; }
  TF_ROUND(13) TF_ROUND(15) TF_ROUND(26) TF_ROUND(6)
  x0 += ks1; x1 += ks2 + 1u;
  TF_ROUND(17) TF_ROUND(29) TF_ROUND(16) TF_ROUND(24)
  x0 += ks2; x1 += ks0 + 2u;
  TF_ROUND(13) TF_ROUND(15) TF_ROUND(26) TF_ROUND(6)
  x0 += ks0; x1 += ks1 + 3u;
  TF_ROUND(17) TF_ROUND(29) TF_ROUND(16) TF_ROUND(24)
  x0 += ks1; x1 += ks2 + 4u;
  TF_ROUND(13) TF_ROUND(15) TF_ROUND(26) TF_ROUND(6)
  x0 += ks2; x1 += ks0 + 5u;
#undef TF_ROUND
  return x0 ^ x1;
}

// ---------------- Stage 6: aggregate (wave/node, 8 edges, butterfly RS) -------
__global__ __launch_bounds__(256) void gcn_aggregate(const int* __restrict__ row_start,
                                                     const int2* __restrict__ eg,
                                                     const unsigned short* __restrict__ support_h,
                                                     const float* __restrict__ b,
                                                     float* __restrict__ out) {
  const int node = (int)((blockIdx.x * 256u + threadIdx.x) >> 6);
  const int lane = threadIdx.x & 63;
  const int grp = lane >> 3;     // edge slot 0..7
  const int sub = lane & 7;      // 8 bf16 feats each (16 B)
  const int s = row_start[node];
  const int e = row_start[node + 1];
  float acc[8];
#pragma unroll
  for (int j = 0; j < 8; ++j) acc[j] = 0.f;
  for (int i = s; i < e; i += 8) {
    const int idx = i + grp;
    const int2 p = (idx < e) ? eg[idx] : make_int2(0, 0);  // val 0 pad -> no-op
    const uint4 q = ((const uint4*)support_h)[(size_t)p.x * 8 + sub];
    const float v = __int_as_float(p.y);
    acc[0] = __builtin_fmaf(v, __uint_as_float(q.x << 16), acc[0]);
    acc[1] = __builtin_fmaf(v, __uint_as_float(q.x & 0xffff0000u), acc[1]);
    acc[2] = __builtin_fmaf(v, __uint_as_float(q.y << 16), acc[2]);
    acc[3] = __builtin_fmaf(v, __uint_as_float(q.y & 0xffff0000u), acc[3]);
    acc[4] = __builtin_fmaf(v, __uint_as_float(q.z << 16), acc[4]);
    acc[5] = __builtin_fmaf(v, __uint_as_float(q.z & 0xffff0000u), acc[5]);
    acc[6] = __builtin_fmaf(v, __uint_as_float(q.w << 16), acc[6]);
    acc[7] = __builtin_fmaf(v, __uint_as_float(q.w & 0xffff0000u), acc[7]);
  }
  // Butterfly reduce-scatter over grp bits, keeping j = grp.
  // acc[j] holds feat sub*8+j; final lane holds full sum for feat sub*8+grp.
  const int g0 = grp & 1, g1 = (grp >> 1) & 1, g2 = grp >> 2;
  float v4[4];
#pragma unroll
  for (int i = 0; i < 4; ++i) {
    const float keep = g0 ? acc[2 * i + 1] : acc[2 * i];
    const float give = g0 ? acc[2 * i] : acc[2 * i + 1];
    v4[i] = keep + __shfl_xor(give, 8);
  }
  float v2[2];
#pragma unroll
  for (int i = 0; i < 2; ++i) {
    const float keep = g1 ? v4[2 * i + 1] : v4[2 * i];
    const float give = g1 ? v4[2 * i] : v4[2 * i + 1];
    v2[i] = keep + __shfl_xor(give, 16);
  }
  const float keep = g2 ? v2[1] : v2[0];
  const float give = g2 ? v2[0] : v2[1];
  const float aval = keep + __shfl_xor(give, 32);
  const int feat = (sub << 3) | grp;
  const float h = fmaxf(aval + b[feat], 0.f);
  const unsigned idxg = (unsigned)node * 64u + (unsigned)feat;
  const bool keepm = (threefry_draw(idxg) >> 31) == 0u;
  out[idxg] = keepm ? h * 2.0f : 0.0f;
}

extern "C" void kernel_launch(void* const* d_in, const int* in_sizes, int n_in,
                              void* d_out, int out_size, void* d_ws, size_t ws_size,
                              hipStream_t stream) {
  const float* x     = (const float*)d_in[0];
  const int*   erow  = (const int*)d_in[1];
  const int*   ecol  = (const int*)d_in[2];
  const float* eval_ = (const float*)d_in[3];
  const float* W     = (const float*)d_in[4];
  const float* b     = (const float*)d_in[5];
  float* out = (float*)d_out;

  // Workspace layout (bytes, 16-aligned), total ~39.4 MB:
  char* ws = (char*)d_ws;
  unsigned short* support_h = (unsigned short*)(ws);      // 12,800,000 (bf16)
  unsigned short* wt        = (unsigned short*)(ws + 12800000);  // 16,384 (bf16 W^T)
  int2*  eg       = (int2*)(ws + 25600000);               // 12,800,000
  int*   hist_g   = (int*)(ws + 38400000);                //    611,524
  int*   tot      = (int*)(ws + 39011536);                //      1,564
  int*   bstart   = (int*)(ws + 39013104);                //      1,568
  int*   row_start= (int*)(ws + 39014672);                //    400,004

  hipLaunchKernelGGL(gcn_wt, dim3(32), dim3(256), 0, stream, W, wt);
  hipLaunchKernelGGL(gcn_gemm, dim3((N_NODES + 63) / 64), dim3(256), 0, stream,
                     x, wt, support_h);
  hipLaunchKernelGGL(gcn_bucket_hist, dim3(NBATCH), dim3(512), 0, stream, erow, hist_g);
  hipLaunchKernelGGL(gcn_colscan, dim3(NBUCK), dim3(512), 0, stream, hist_g, tot);
  hipLaunchKernelGGL(gcn_bucket_scan, dim3(1), dim3(512), 0, stream, tot, bstart, row_start);
  hipLaunchKernelGGL(gcn_bin, dim3(NBATCH), dim3(512), 0, stream,
                     erow, ecol, eval_, hist_g, bstart, eg);
  hipLaunchKernelGGL(gcn_rowsort, dim3(NBUCK), dim3(512), 0, stream,
                     bstart, eg, row_start);
  hipLaunchKernelGGL(gcn_aggregate, dim3(N_NODES / 4), dim3(256), 0, stream,
                     row_start, eg, support_h, b, out);
}